// Round 1
// baseline (394.134 us; speedup 1.0000x reference)
//
#include <hip/hip_runtime.h>

#define CCH 64
#define NPIX 65536
#define LDSW 76   // LDS row stride (floats): 16B-aligned (76*4=304), %32==12 -> <=2-way conflicts

// ---------------- Kernel A: partial Gram (split over N), atomic accumulate ----------------
__global__ __launch_bounds__(256) void gram_kernel(const float* __restrict__ x,
                                                   float* __restrict__ gram) {
    __shared__ float xs[64][LDSW];
    const int b = blockIdx.y;
    const int t = threadIdx.x;
    const int NB = NPIX / gridDim.x;
    const int n0 = blockIdx.x * NB;
    const float* xb = x + (size_t)b * CCH * NPIX;

    const int c0 = 4 * (t >> 4);   // 4x4 output tile: rows c0..c0+3
    const int d0 = 4 * (t & 15);   // cols d0..d0+3

    float acc[4][4] = {};

    for (int tile = 0; tile < NB / 64; ++tile) {
        const int nt = n0 + tile * 64;
        __syncthreads();
        // stage x[b, 0:64, nt:nt+64] transposed into xs[n][c]
        #pragma unroll
        for (int i = 0; i < 4; ++i) {
            int l = t + i * 256;        // 0..1023
            int c = l >> 4;             // 0..63
            int q = l & 15;             // 0..15 -> 4 n-values
            float4 v = *reinterpret_cast<const float4*>(xb + (size_t)c * NPIX + nt + 4 * q);
            xs[4 * q + 0][c] = v.x;
            xs[4 * q + 1][c] = v.y;
            xs[4 * q + 2][c] = v.z;
            xs[4 * q + 3][c] = v.w;
        }
        __syncthreads();
        #pragma unroll 8
        for (int n = 0; n < 64; ++n) {
            float4 a = *reinterpret_cast<const float4*>(&xs[n][c0]);
            float4 bb = *reinterpret_cast<const float4*>(&xs[n][d0]);
            float av[4] = {a.x, a.y, a.z, a.w};
            float bv[4] = {bb.x, bb.y, bb.z, bb.w};
            #pragma unroll
            for (int i = 0; i < 4; ++i)
                #pragma unroll
                for (int j = 0; j < 4; ++j)
                    acc[i][j] += av[i] * bv[j];
        }
    }
    float* g = gram + b * (CCH * CCH);
    #pragma unroll
    for (int i = 0; i < 4; ++i)
        #pragma unroll
        for (int j = 0; j < 4; ++j)
            atomicAdd(&g[(c0 + i) * CCH + (d0 + j)], acc[i][j]);
}

// ---------------- Kernel B: normalize + SE bottleneck + softmax (one block per batch) -----
__global__ __launch_bounds__(256) void se_softmax_kernel(const float* __restrict__ gram,
                                                         const float* __restrict__ W1,
                                                         const float* __restrict__ b1,
                                                         const float* __restrict__ W2,
                                                         const float* __restrict__ b2,
                                                         float* __restrict__ attn) {
    __shared__ float e[4096];
    __shared__ float rs[64];
    __shared__ float hbuf[16];
    __shared__ float pp[16][17];
    __shared__ float rowred[64];
    const int b = blockIdx.x;
    const int t = threadIdx.x;
    const float* g = gram + b * 4096;

    if (t < 64) rs[t] = rsqrtf(g[t * 65]);  // diag entry g[t*64 + t]
    __syncthreads();

    for (int l = t; l < 4096; l += 256) {
        int c = l >> 6, d = l & 63;
        e[l] = g[l] * rs[c] * rs[d];
    }
    __syncthreads();

    // h = relu(W1 @ e + b1), W1 is (16, 4096)
    {
        int o = t & 15, gr = t >> 4;
        float s = 0.f;
        const float* w = W1 + o * 4096 + gr * 256;
        const float* ee = e + gr * 256;
        for (int j = 0; j < 256; ++j) s += w[j] * ee[j];
        pp[gr][o] = s;
    }
    __syncthreads();
    if (t < 16) {
        float s = b1[t];
        #pragma unroll
        for (int gr = 0; gr < 16; ++gr) s += pp[gr][t];
        hbuf[t] = fmaxf(s, 0.f);
    }
    __syncthreads();

    // energy2 = W2 @ h + b2, W2 is (4096, 16); store back into e
    {
        float hv[16];
        #pragma unroll
        for (int o = 0; o < 16; ++o) hv[o] = hbuf[o];
        for (int l = t; l < 4096; l += 256) {
            const float* w = W2 + (size_t)l * 16;
            float s = b2[l];
            #pragma unroll
            for (int o = 0; o < 16; ++o) s += w[o] * hv[o];
            e[l] = s;
        }
    }
    __syncthreads();

    // softmax(rowmax - e) over d  ==  exp(rowmin - e) / sum
    {
        int r = t >> 2, q = t & 3;
        float mn = INFINITY;
        for (int j = 0; j < 16; ++j) mn = fminf(mn, e[r * 64 + q * 16 + j]);
        mn = fminf(mn, __shfl_xor(mn, 1));
        mn = fminf(mn, __shfl_xor(mn, 2));
        if (q == 0) rowred[r] = mn;
    }
    __syncthreads();
    for (int l = t; l < 4096; l += 256) {
        int c = l >> 6;
        e[l] = expf(rowred[c] - e[l]);
    }
    __syncthreads();
    {
        int r = t >> 2, q = t & 3;
        float s = 0.f;
        for (int j = 0; j < 16; ++j) s += e[r * 64 + q * 16 + j];
        s += __shfl_xor(s, 1);
        s += __shfl_xor(s, 2);
        if (q == 0) rowred[r] = 1.0f / s;
    }
    __syncthreads();
    float* ab = attn + b * 4096;
    for (int l = t; l < 4096; l += 256) {
        int c = l >> 6;
        ab[l] = e[l] * rowred[c];
    }
}

// ---------------- Kernel C: out = gamma * (attn @ x) + x ----------------
__global__ __launch_bounds__(256) void apply_kernel(const float* __restrict__ x,
                                                    const float* __restrict__ attn,
                                                    const float* __restrict__ gamma,
                                                    float* __restrict__ out) {
    __shared__ float xs[64][LDSW];   // xs[n][d]
    __shared__ float at[64][LDSW];   // at[c][d]
    const int b = blockIdx.y;
    const int t = threadIdx.x;
    const int NB = NPIX / gridDim.x;
    const int n0 = blockIdx.x * NB;
    const float gm = gamma[0];
    const float* xb = x + (size_t)b * CCH * NPIX;
    float* ob = out + (size_t)b * CCH * NPIX;

    // stage attention matrix once
    #pragma unroll
    for (int i = 0; i < 4; ++i) {
        int l = 4 * (t + i * 256);   // 0..4092 step 4
        int c = l >> 6, d = l & 63;
        float4 v = *reinterpret_cast<const float4*>(attn + b * 4096 + l);
        at[c][d + 0] = v.x;
        at[c][d + 1] = v.y;
        at[c][d + 2] = v.z;
        at[c][d + 3] = v.w;
    }

    const int tc4 = 4 * (t >> 4);   // output rows (c)
    const int tn4 = 4 * (t & 15);   // output cols within tile (n)

    for (int tile = 0; tile < NB / 64; ++tile) {
        const int nt = n0 + tile * 64;
        __syncthreads();   // protects xs (prev iter) and covers at-staging on iter 0
        #pragma unroll
        for (int i = 0; i < 4; ++i) {
            int l = t + i * 256;
            int c = l >> 4;
            int q = l & 15;
            float4 v = *reinterpret_cast<const float4*>(xb + (size_t)c * NPIX + nt + 4 * q);
            xs[4 * q + 0][c] = v.x;
            xs[4 * q + 1][c] = v.y;
            xs[4 * q + 2][c] = v.z;
            xs[4 * q + 3][c] = v.w;
        }
        __syncthreads();

        float acc[4][4] = {};
        #pragma unroll 4
        for (int d = 0; d < 64; d += 4) {
            float4 Av[4], Xv[4];
            #pragma unroll
            for (int i = 0; i < 4; ++i) Av[i] = *reinterpret_cast<const float4*>(&at[tc4 + i][d]);
            #pragma unroll
            for (int j = 0; j < 4; ++j) Xv[j] = *reinterpret_cast<const float4*>(&xs[tn4 + j][d]);
            #pragma unroll
            for (int i = 0; i < 4; ++i)
                #pragma unroll
                for (int j = 0; j < 4; ++j)
                    acc[i][j] += Av[i].x * Xv[j].x + Av[i].y * Xv[j].y +
                                 Av[i].z * Xv[j].z + Av[i].w * Xv[j].w;
        }

        // epilogue: out = gamma*acc + x (residual read from xs transposed)
        #pragma unroll
        for (int i = 0; i < 4; ++i) {
            float4 o;
            o.x = gm * acc[i][0] + xs[tn4 + 0][tc4 + i];
            o.y = gm * acc[i][1] + xs[tn4 + 1][tc4 + i];
            o.z = gm * acc[i][2] + xs[tn4 + 2][tc4 + i];
            o.w = gm * acc[i][3] + xs[tn4 + 3][tc4 + i];
            *reinterpret_cast<float4*>(ob + (size_t)(tc4 + i) * NPIX + nt + tn4) = o;
        }
    }
}

extern "C" void kernel_launch(void* const* d_in, const int* in_sizes, int n_in,
                              void* d_out, int out_size, void* d_ws, size_t ws_size,
                              hipStream_t stream) {
    const float* x     = (const float*)d_in[0];
    const float* W1    = (const float*)d_in[1];
    const float* b1    = (const float*)d_in[2];
    const float* W2    = (const float*)d_in[3];
    const float* b2    = (const float*)d_in[4];
    const float* gamma = (const float*)d_in[5];
    float* out = (float*)d_out;

    float* gram = (float*)d_ws;              // 8*4096 floats
    float* attn = gram + 8 * 4096;           // 8*4096 floats

    hipMemsetAsync(d_ws, 0, 8 * 4096 * sizeof(float), stream);

    gram_kernel<<<dim3(128, 8), 256, 0, stream>>>(x, gram);
    se_softmax_kernel<<<8, 256, 0, stream>>>(gram, W1, b1, W2, b2, attn);
    apply_kernel<<<dim3(128, 8), 256, 0, stream>>>(x, attn, gamma, out);
}

// Round 2
// 305.951 us; speedup vs baseline: 1.2882x; 1.2882x over previous
//
#include <hip/hip_runtime.h>
#include <hip/hip_bf16.h>

#define CCH 64
#define NPIX 65536
#define NSPLIT 128
#define NB (NPIX / NSPLIT)   // 512 n-values per block

typedef short bf16x8 __attribute__((ext_vector_type(8)));
typedef float f32x16 __attribute__((ext_vector_type(16)));

static __device__ inline short f2bf(float f) {
    union { __hip_bfloat16 h; short s; } u;
    u.h = __float2bfloat16(f);
    return u.s;
}

static __device__ inline bf16x8 cvt8(float4 a, float4 b) {
    bf16x8 r;
    r[0] = f2bf(a.x); r[1] = f2bf(a.y); r[2] = f2bf(a.z); r[3] = f2bf(a.w);
    r[4] = f2bf(b.x); r[5] = f2bf(b.y); r[6] = f2bf(b.z); r[7] = f2bf(b.w);
    return r;
}

// ---------------- Kernel A: Gram via MFMA, no LDS, no transpose ----------------
// Trick: for D = X·X^T, the MFMA B-fragment of column-block d equals the
// A-fragment of row-block d (both are lane=(row/col)&31, k-contiguous 8).
__global__ __launch_bounds__(256) void gram_kernel(const float* __restrict__ x,
                                                   float* __restrict__ gram) {
    const int b    = blockIdx.y;
    const int t    = threadIdx.x;
    const int wave = t >> 6, lane = t & 63;
    const int qi = wave >> 1, qj = wave & 1;       // 32x32 quadrant of 64x64 output
    const int lrow = lane & 31, khalf = lane >> 5; // fragment row / k-half

    const float* xb = x + (size_t)b * CCH * NPIX;
    const int n0 = blockIdx.x * NB;
    const float* pa = xb + (size_t)(32 * qi + lrow) * NPIX + n0 + khalf * 8;
    const float* pb = xb + (size_t)(32 * qj + lrow) * NPIX + n0 + khalf * 8;

    f32x16 acc = {};
    #pragma unroll 4
    for (int k = 0; k < NB; k += 16) {
        float4 a0 = *(const float4*)(pa + k);
        float4 a1 = *(const float4*)(pa + k + 4);
        float4 b0 = *(const float4*)(pb + k);
        float4 b1 = *(const float4*)(pb + k + 4);
        acc = __builtin_amdgcn_mfma_f32_32x32x16_bf16(cvt8(a0, a1), cvt8(b0, b1), acc, 0, 0, 0);
    }

    float* g = gram + b * 4096;
    #pragma unroll
    for (int r = 0; r < 16; ++r) {
        // C/D layout (m74/m101): col = lane&31, row = (r&3) + 8*(r>>2) + 4*(lane>>5)
        int row = 32 * qi + 4 * khalf + (r & 3) + 8 * (r >> 2);
        atomicAdd(&g[row * 64 + 32 * qj + lrow], acc[r]);
    }
}

// ---------------- Kernel B: normalize + SE bottleneck + softmax (vectorized) ----
__global__ __launch_bounds__(256) void se_softmax_kernel(const float* __restrict__ gram,
                                                         const float* __restrict__ W1,
                                                         const float* __restrict__ b1,
                                                         const float* __restrict__ W2,
                                                         const float* __restrict__ b2,
                                                         float* __restrict__ attn) {
    __shared__ float e[4096];
    __shared__ float rs[64];
    __shared__ float hbuf[16];
    __shared__ float pw[4][16];
    __shared__ float rowred[64];
    const int b = blockIdx.x;
    const int t = threadIdx.x;
    const int wave = t >> 6, lane = t & 63;
    const float* g = gram + b * 4096;

    if (t < 64) rs[t] = rsqrtf(g[t * 65]);
    __syncthreads();

    // cosine-normalize into e[]
    #pragma unroll
    for (int j = 0; j < 4; ++j) {
        int l = j * 1024 + 4 * t;
        float4 gv = *(const float4*)(g + l);
        int c = l >> 6, d = l & 63;
        float rc = rs[c];
        float4 ev;
        ev.x = gv.x * rc * rs[d + 0];
        ev.y = gv.y * rc * rs[d + 1];
        ev.z = gv.z * rc * rs[d + 2];
        ev.w = gv.w * rc * rs[d + 3];
        *(float4*)(e + l) = ev;
    }
    __syncthreads();

    // h = relu(W1 @ e + b1): per-thread float4 partials for all 16 outputs
    float acc[16] = {};
    #pragma unroll
    for (int j = 0; j < 4; ++j) {
        float4 ev = *(const float4*)(e + j * 1024 + 4 * t);
        #pragma unroll
        for (int o = 0; o < 16; ++o) {
            float4 wv = *(const float4*)(W1 + o * 4096 + j * 1024 + 4 * t);
            acc[o] += wv.x * ev.x + wv.y * ev.y + wv.z * ev.z + wv.w * ev.w;
        }
    }
    #pragma unroll
    for (int o = 0; o < 16; ++o) {
        #pragma unroll
        for (int off = 1; off < 64; off <<= 1)
            acc[o] += __shfl_xor(acc[o], off);
    }
    if (lane == 0) {
        #pragma unroll
        for (int o = 0; o < 16; ++o) pw[wave][o] = acc[o];
    }
    __syncthreads();
    if (t < 16) {
        float s = b1[t] + pw[0][t] + pw[1][t] + pw[2][t] + pw[3][t];
        hbuf[t] = fmaxf(s, 0.f);
    }
    __syncthreads();

    // energy2 = W2 @ h + b2  (W2 rows contiguous: 4x float4)
    float hv[16];
    #pragma unroll
    for (int o = 0; o < 16; ++o) hv[o] = hbuf[o];
    for (int l = t; l < 4096; l += 256) {
        const float* w = W2 + (size_t)l * 16;
        float4 w0 = *(const float4*)(w);
        float4 w1v = *(const float4*)(w + 4);
        float4 w2v = *(const float4*)(w + 8);
        float4 w3v = *(const float4*)(w + 12);
        float s = b2[l]
            + w0.x * hv[0]  + w0.y * hv[1]  + w0.z * hv[2]  + w0.w * hv[3]
            + w1v.x * hv[4] + w1v.y * hv[5] + w1v.z * hv[6] + w1v.w * hv[7]
            + w2v.x * hv[8] + w2v.y * hv[9] + w2v.z * hv[10] + w2v.w * hv[11]
            + w3v.x * hv[12] + w3v.y * hv[13] + w3v.z * hv[14] + w3v.w * hv[15];
        e[l] = s;
    }
    __syncthreads();

    // softmax(rowmax - e) over d  ==  exp(rowmin - e) / sum
    {
        int r = t >> 2, q = t & 3;
        float mn = INFINITY;
        #pragma unroll
        for (int j = 0; j < 16; ++j) mn = fminf(mn, e[r * 64 + q * 16 + j]);
        mn = fminf(mn, __shfl_xor(mn, 1));
        mn = fminf(mn, __shfl_xor(mn, 2));
        if (q == 0) rowred[r] = mn;
    }
    __syncthreads();
    for (int l = t; l < 4096; l += 256) {
        int c = l >> 6;
        e[l] = expf(rowred[c] - e[l]);
    }
    __syncthreads();
    {
        int r = t >> 2, q = t & 3;
        float s = 0.f;
        #pragma unroll
        for (int j = 0; j < 16; ++j) s += e[r * 64 + q * 16 + j];
        s += __shfl_xor(s, 1);
        s += __shfl_xor(s, 2);
        if (q == 0) rowred[r] = 1.0f / s;
    }
    __syncthreads();
    float* ab = attn + b * 4096;
    for (int l = t; l < 4096; l += 256) {
        int c = l >> 6;
        ab[l] = e[l] * rowred[c];
    }
}

// ---------------- Kernel C: out = gamma * (attn @ x) + x via MFMA, no LDS -------
__global__ __launch_bounds__(256) void apply_kernel(const float* __restrict__ x,
                                                    const float* __restrict__ attn,
                                                    const float* __restrict__ gamma,
                                                    float* __restrict__ out) {
    const int b    = blockIdx.y;
    const int t    = threadIdx.x;
    const int wave = t >> 6, lane = t & 63;
    const int ci = wave >> 1, nj = wave & 1;       // c-block (rows), n sub-block
    const int lrow = lane & 31, khalf = lane >> 5;
    const float gm = gamma[0];
    const float* xb = x + (size_t)b * CCH * NPIX;
    float* ob = out + (size_t)b * CCH * NPIX;

    // hoist attention A-fragments (constant over n)
    const float* arow = attn + b * 4096 + (32 * ci + lrow) * 64 + khalf * 8;
    bf16x8 afrag[4];
    #pragma unroll
    for (int ks = 0; ks < 4; ++ks) {
        float4 a0 = *(const float4*)(arow + ks * 16);
        float4 a1 = *(const float4*)(arow + ks * 16 + 4);
        afrag[ks] = cvt8(a0, a1);
    }

    const int n0 = blockIdx.x * NB;
    for (int it = 0; it < NB / 64; ++it) {
        const int nc = n0 + it * 64 + nj * 32 + lrow;
        f32x16 acc = {};
        #pragma unroll
        for (int ks = 0; ks < 4; ++ks) {
            const int r0 = ks * 16 + khalf * 8;
            bf16x8 bfrag;
            #pragma unroll
            for (int i = 0; i < 8; ++i)
                bfrag[i] = f2bf(xb[(size_t)(r0 + i) * NPIX + nc]);
            acc = __builtin_amdgcn_mfma_f32_32x32x16_bf16(afrag[ks], bfrag, acc, 0, 0, 0);
        }
        #pragma unroll
        for (int r = 0; r < 16; ++r) {
            int c = 32 * ci + 4 * khalf + (r & 3) + 8 * (r >> 2);
            size_t off = (size_t)c * NPIX + nc;
            ob[off] = gm * acc[r] + xb[off];
        }
    }
}

extern "C" void kernel_launch(void* const* d_in, const int* in_sizes, int n_in,
                              void* d_out, int out_size, void* d_ws, size_t ws_size,
                              hipStream_t stream) {
    const float* x     = (const float*)d_in[0];
    const float* W1    = (const float*)d_in[1];
    const float* b1    = (const float*)d_in[2];
    const float* W2    = (const float*)d_in[3];
    const float* b2    = (const float*)d_in[4];
    const float* gamma = (const float*)d_in[5];
    float* out = (float*)d_out;

    float* gram = (float*)d_ws;              // 8*4096 floats
    float* attn = gram + 8 * 4096;           // 8*4096 floats

    hipMemsetAsync(d_ws, 0, 8 * 4096 * sizeof(float), stream);

    gram_kernel<<<dim3(NSPLIT, 8), 256, 0, stream>>>(x, gram);
    se_softmax_kernel<<<8, 256, 0, stream>>>(gram, W1, b1, W2, b2, attn);
    apply_kernel<<<dim3(NSPLIT, 8), 256, 0, stream>>>(x, attn, gamma, out);
}